// Round 12
// baseline (62.450 us; speedup 1.0000x reference)
//
#include <hip/hip_runtime.h>
#include <stdint.h>

#define CLASS_NUM 7
#define QROWS 1050
#define QPAD  1152              // 72 groups * 16 rows; pad rows are zero
#define NPAD  102               // pad rows each add exp2(0)=1 to denom
#define NGRP  72
#define GPW   18                // groups per wave (NGRP / 4 waves)
#define QSUM_OFF 147456         // 7x128 fp32 class sums (after fp8 queue image)
#define A_OFF    151552         // fp8 A fragment-image, 65536 rows -> 8 MB
#define LPOS_OFF (A_OFF + (1 << 23))      // float[65536]
#define PD_OFF   (LPOS_OFF + (1 << 18))   // float[65536]
#define C2L 2.8853900817779268f // 2/ln2 : exp(2s) = exp2(s*C2L)

typedef float f32x4 __attribute__((ext_vector_type(4)));
typedef long  long2v __attribute__((ext_vector_type(2)));

// pack 4 floats -> 4 fp8 e4m3 (OCP, RNE) in one dword
__device__ __forceinline__ unsigned pk8(float a, float b, float c, float d) {
  int v = __builtin_amdgcn_cvt_pk_fp8_f32(a, b, 0, false);
  v = __builtin_amdgcn_cvt_pk_fp8_f32(c, d, v, true);
  return (unsigned)v;
}

// ---- prep 1: (a) queue fp32 -> fp8 fragment-major image [g][lane][k];
// (b) per-class column sums via run-based atomics (qsum zeroed by memset).
__global__ __launch_bounds__(256) void prep_q8(
    const float* __restrict__ queue, char* __restrict__ ws)
{
  const int g = blockIdx.x, tid = threadIdx.x;
  {
    const int lane = tid >> 2, k = tid & 3;
    const int row = g * 16 + (lane & 15);
    const int col = k * 32 + (lane >> 4) * 8;
    uint2 u = {0u, 0u};
    if (row < QROWS) {
      const float4 v0 = *(const float4*)(queue + row * 128 + col);
      const float4 v1 = *(const float4*)(queue + row * 128 + col + 4);
      u.x = pk8(v0.x, v0.y, v0.z, v0.w);
      u.y = pk8(v1.x, v1.y, v1.z, v1.w);
    }
    *(uint2*)(ws + (size_t)g * 2048 + tid * 8) = u;
  }
  {
    float* qsum = (float*)(ws + QSUM_OFF);
    const int col = tid & 127;
    const int rbase = g * 16 + (tid >> 7) * 8;
    int c0 = -1; float s = 0.f;
#pragma unroll
    for (int rr = 0; rr < 8; ++rr) {
      const int row = rbase + rr;
      if (row < QROWS) {
        const int c = (row * 6991) >> 20;          // row/150, exact here
        if (c != c0) {
          if (c0 >= 0) atomicAdd(&qsum[c0 * 128 + col], s);
          c0 = c; s = 0.f;
        }
        s += queue[row * 128 + col];
      }
    }
    if (c0 >= 0) atomicAdd(&qsum[c0 * 128 + col], s);
  }
}

// ---- prep 2: per-row stats + fp8 A fragment-image. Pure-BW, high occupancy.
// 8 threads/row, 32 rows/block, 2048 blocks.
__global__ __launch_bounds__(256) void prep_act(
    const float* __restrict__ act, const float* __restrict__ ema,
    const float* __restrict__ plab, char* __restrict__ ws)
{
  const int tid = threadIdx.x;
  const int r = tid >> 3, j8 = tid & 7;
  const long grow = (long)blockIdx.x * 32 + r;
  const float* ap = act + grow * 128 + j8 * 16;
  const float* ep = ema + grow * 128 + j8 * 16;

  float pv = (j8 < CLASS_NUM) ? plab[grow * CLASS_NUM + j8] : -3.4e38f;
  f32x4 a4[4], e4[4];
#pragma unroll
  for (int u = 0; u < 4; ++u) a4[u] = *(const f32x4*)(ap + 4 * u);
#pragma unroll
  for (int u = 0; u < 4; ++u) e4[u] = *(const f32x4*)(ep + 4 * u);

  float a2 = 0.f, e2 = 0.f, ae = 0.f;
#pragma unroll
  for (int u = 0; u < 4; ++u) {
    a2 += a4[u].x*a4[u].x + a4[u].y*a4[u].y + a4[u].z*a4[u].z + a4[u].w*a4[u].w;
    e2 += e4[u].x*e4[u].x + e4[u].y*e4[u].y + e4[u].z*e4[u].z + e4[u].w*e4[u].w;
    ae += a4[u].x*e4[u].x + a4[u].y*e4[u].y + a4[u].z*e4[u].z + a4[u].w*e4[u].w;
  }
#pragma unroll
  for (int m = 1; m < 8; m <<= 1) {
    a2 += __shfl_xor(a2, m);
    e2 += __shfl_xor(e2, m);
    ae += __shfl_xor(ae, m);
  }
  const float rna = rsqrtf(a2), rne = rsqrtf(e2);

  // argmax over 7 classes via 8-lane vote (first-max tie rule)
  int bi = j8;
#pragma unroll
  for (int m = 1; m < 8; m <<= 1) {
    const float ov = __shfl_xor(pv, m);
    const int   oi = __shfl_xor(bi, m);
    if (ov > pv || (ov == pv && oi < bi)) { pv = ov; bi = oi; }
  }

  // positive-sum via precomputed class sums (fp32-exact)
  const float* qs = (const float*)(ws + QSUM_OFF) + bi * 128 + j8 * 16;
  float pdot = 0.f;
#pragma unroll
  for (int u = 0; u < 4; ++u) {
    const float4 qv = *(const float4*)(qs + 4 * u);
    pdot += a4[u].x*qv.x + a4[u].y*qv.y + a4[u].z*qv.z + a4[u].w*qv.w;
  }
#pragma unroll
  for (int m = 1; m < 8; m <<= 1) pdot += __shfl_xor(pdot, m);

  if (j8 == 0) {
    ((float*)(ws + LPOS_OFF))[grow] = ae * rna * rne * C2L;
    ((float*)(ws + PD_OFF))[grow]   = pdot * rna;
  }

  // A fragment-image write: set G = grow>>4, lane row lr = grow&15.
  // chunk c = 2*j8+h2 -> k = c>>2, hi_ = c&3; addr = G*2048 + (hi_*16+lr)*32 + k*8
  const float sc = rna * C2L;     // pre-scale so MFMA output is 2s/ln2
  const int G = (int)(grow >> 4), lr = (int)(grow & 15);
  const int k = j8 >> 1;
#pragma unroll
  for (int h2 = 0; h2 < 2; ++h2) {
    const int hi_ = (j8 & 1) * 2 + h2;
    const f32x4 x = a4[h2 * 2], y = a4[h2 * 2 + 1];
    uint2 u;
    u.x = pk8(x.x * sc, x.y * sc, x.z * sc, x.w * sc);
    u.y = pk8(y.x * sc, y.y * sc, y.z * sc, y.w * sc);
    *(uint2*)(ws + A_OFF + (size_t)G * 2048 + (hi_ * 16 + lr) * 32 + k * 8) = u;
  }
}

// ---- main sweep: 2048 blocks x 256 thr (4 waves). Block owns 32 rows (2
// fragment sets read straight from the A-image, coalesced); each wave sweeps
// a quarter of the queue. No prologue, no LDS tile -> pure streaming.
__global__ __launch_bounds__(256) void pgc_sweep(
    const char* __restrict__ ws, float* __restrict__ out)
{
  __shared__ float dnp[4][32];

  const int tid = threadIdx.x, lane = tid & 63, wave = tid >> 6;
  const int lo = lane & 15, hi = lane >> 4;

  // A fragments: 2 row-sets, 2 KB each, lane-contiguous
  const char* Ab = ws + A_OFF + (size_t)blockIdx.x * 4096;
  const long2v la0 = *(const long2v*)(Ab + lane * 32);
  const long2v la1 = *(const long2v*)(Ab + lane * 32 + 16);
  const long2v lb0 = *(const long2v*)(Ab + 2048 + lane * 32);
  const long2v lb1 = *(const long2v*)(Ab + 2048 + lane * 32 + 16);

  float dn0[4] = {0.f, 0.f, 0.f, 0.f};
  float dn1[4] = {0.f, 0.f, 0.f, 0.f};
  const f32x4 Z = {0.f, 0.f, 0.f, 0.f};
  const char* qp = ws + (size_t)(wave * GPW) * 2048 + (size_t)lane * 32;

  long2v B0a, B0b, B1a, B1b;
#define LOADG(Xa, Xb, G)                                                \
  { Xa = *(const long2v*)(qp + (G) * 2048);                             \
    Xb = *(const long2v*)(qp + (G) * 2048 + 16); }
#define COMPG(Xa, Xb)                                                   \
  { f32x4 c0 = Z, c1 = Z;                                               \
    c0 = __builtin_amdgcn_mfma_f32_16x16x32_fp8_fp8(la0[0], Xa[0], c0, 0, 0, 0); \
    c1 = __builtin_amdgcn_mfma_f32_16x16x32_fp8_fp8(lb0[0], Xa[0], c1, 0, 0, 0); \
    c0 = __builtin_amdgcn_mfma_f32_16x16x32_fp8_fp8(la0[1], Xa[1], c0, 0, 0, 0); \
    c1 = __builtin_amdgcn_mfma_f32_16x16x32_fp8_fp8(lb0[1], Xa[1], c1, 0, 0, 0); \
    c0 = __builtin_amdgcn_mfma_f32_16x16x32_fp8_fp8(la1[0], Xb[0], c0, 0, 0, 0); \
    c1 = __builtin_amdgcn_mfma_f32_16x16x32_fp8_fp8(lb1[0], Xb[0], c1, 0, 0, 0); \
    c0 = __builtin_amdgcn_mfma_f32_16x16x32_fp8_fp8(la1[1], Xb[1], c0, 0, 0, 0); \
    c1 = __builtin_amdgcn_mfma_f32_16x16x32_fp8_fp8(lb1[1], Xb[1], c1, 0, 0, 0); \
    _Pragma("unroll")                                                   \
    for (int rg = 0; rg < 4; ++rg) {                                    \
      dn0[rg] += exp2f(c0[rg]);                                         \
      dn1[rg] += exp2f(c1[rg]);                                         \
    } }

  LOADG(B0a, B0b, 0)
  LOADG(B1a, B1b, 1)
#pragma unroll 1
  for (int g = 0; g < GPW - 2; g += 2) {
    COMPG(B0a, B0b) LOADG(B0a, B0b, g + 2)
    COMPG(B1a, B1b) LOADG(B1a, B1b, g + 3)
  }
  COMPG(B0a, B0b)
  COMPG(B1a, B1b)
#undef LOADG
#undef COMPG

  // reduce across the 16 q-column lanes of each row
#pragma unroll
  for (int rg = 0; rg < 4; ++rg)
#pragma unroll
    for (int m = 1; m < 16; m <<= 1) {
      dn0[rg] += __shfl_xor(dn0[rg], m);
      dn1[rg] += __shfl_xor(dn1[rg], m);
    }

  if (lo == 0) {
#pragma unroll
    for (int rg = 0; rg < 4; ++rg) {
      dnp[wave][hi * 4 + rg]      = dn0[rg];
      dnp[wave][16 + hi * 4 + rg] = dn1[rg];
    }
  }
  __syncthreads();

  // epilogue: thread i (< 32) owns block-row i
  if (tid < 32) {
    const int i = tid;
    const int R = blockIdx.x * 32 + i;
    const float dtot = dnp[0][i] + dnp[1][i] + dnp[2][i] + dnp[3][i];
    const float lp   = exp2f(((const float*)(ws + LPOS_OFF))[R]);
    const float pdr  = ((const float*)(ws + PD_OFF))[R];
    const float dnf  = lp + dtot - (float)NPAD;
    float loss = -logf(lp / dnf + 1e-8f) + 150.0f * logf(dnf) - 2.0f * pdr;
#pragma unroll
    for (int m = 1; m < 32; m <<= 1) loss += __shfl_xor(loss, m);
    if (tid == 0)
      atomicAdd(out, loss * (1.0f / (151.0f * 65536.0f)));
  }
}

extern "C" void kernel_launch(void* const* d_in, const int* in_sizes, int n_in,
                              void* d_out, int out_size, void* d_ws, size_t ws_size,
                              hipStream_t stream) {
  const float* act   = (const float*)d_in[0];
  const float* ema   = (const float*)d_in[1];
  const float* plab  = (const float*)d_in[2];
  const float* queue = (const float*)d_in[3];
  float* out = (float*)d_out;

  hipMemsetAsync(d_out, 0, sizeof(float), stream);
  hipMemsetAsync((char*)d_ws + QSUM_OFF, 0, CLASS_NUM * 128 * sizeof(float), stream);

  prep_q8<<<dim3(NGRP), dim3(256), 0, stream>>>(queue, (char*)d_ws);
  prep_act<<<dim3(2048), dim3(256), 0, stream>>>(act, ema, plab, (char*)d_ws);
  pgc_sweep<<<dim3(2048), dim3(256), 0, stream>>>((const char*)d_ws, out);
}

// Round 13
// 50.541 us; speedup vs baseline: 1.2356x; 1.2356x over previous
//
#include <hip/hip_runtime.h>
#include <stdint.h>

#define CLASS_NUM 7
#define QROWS 1050
#define QPAD  1152              // 72 groups * 16 rows; pad rows are zero
#define NPAD  102               // pad rows each add exp2(0)=1 to denom
#define NGRP  72
#define GPW   18                // groups per wave (one queue quarter)
#define QSUM_OFF (QPAD * 128)   // 147456: 7x128 fp32 class sums (after fp8 image)
#define C2L 2.8853900817779268f // 2/ln2 : exp(2s) = exp2(s*C2L)

typedef float f32x4 __attribute__((ext_vector_type(4)));
typedef long  long2v __attribute__((ext_vector_type(2)));

// pack 4 floats -> 4 fp8 e4m3 (OCP, RNE) in one dword
__device__ __forceinline__ unsigned pk8(float a, float b, float c, float d) {
  int v = __builtin_amdgcn_cvt_pk_fp8_f32(a, b, 0, false);
  v = __builtin_amdgcn_cvt_pk_fp8_f32(c, d, v, true);
  return (unsigned)v;
}

// ---- prep: (a) queue fp32 -> fp8 fragment-major image [g][lane][k];
// (b) per-class column sums via run-based atomics (qsum zeroed by memset).
__global__ __launch_bounds__(256) void prep_q8(
    const float* __restrict__ queue, char* __restrict__ ws)
{
  const int g = blockIdx.x, tid = threadIdx.x;
  {
    const int lane = tid >> 2, k = tid & 3;
    const int row = g * 16 + (lane & 15);
    const int col = k * 32 + (lane >> 4) * 8;
    uint2 u = {0u, 0u};
    if (row < QROWS) {
      const float4 v0 = *(const float4*)(queue + row * 128 + col);
      const float4 v1 = *(const float4*)(queue + row * 128 + col + 4);
      u.x = pk8(v0.x, v0.y, v0.z, v0.w);
      u.y = pk8(v1.x, v1.y, v1.z, v1.w);
    }
    *(uint2*)(ws + (size_t)g * 2048 + tid * 8) = u;
  }
  {
    float* qsum = (float*)(ws + QSUM_OFF);
    const int col = tid & 127;
    const int rbase = g * 16 + (tid >> 7) * 8;
    int c0 = -1; float s = 0.f;
#pragma unroll
    for (int rr = 0; rr < 8; ++rr) {
      const int row = rbase + rr;
      if (row < QROWS) {
        const int c = (row * 6991) >> 20;          // row/150, exact here
        if (c != c0) {
          if (c0 >= 0) atomicAdd(&qsum[c0 * 128 + col], s);
          c0 = c; s = 0.f;
        }
        s += queue[row * 128 + col];
      }
    }
    if (c0 >= 0) atomicAdd(&qsum[c0 * 128 + col], s);
  }
}

// ---- fused main: 1024 blocks x 512 thr (8 waves). Block owns 64 B-rows.
// Wave w: queue-quarter (w&3), row-half (w>>2). Waves w and w+4 share a SIMD
// and sweep the SAME quarter in near-lockstep -> trailing wave hits L1.
// Depth-3 register rotation hides L2 latency (~600 cyc ahead).
__global__ __launch_bounds__(512, 2) void pgc_stream(
    const float* __restrict__ act, const float* __restrict__ ema,
    const float* __restrict__ plab, const char* __restrict__ ws,
    float* __restrict__ out)
{
  __shared__ __align__(16) char aT[8192];    // 64-row fp8 A tile, frag-major
  __shared__ float s_lpos[64], s_pd[64];
  __shared__ float dnp[8][32];

  const int tid = threadIdx.x, lane = tid & 63, wave = tid >> 6;
  const int lo = lane & 15, hi = lane >> 4;

  // ---- prologue: 8 threads/row, 64 rows. Independent loads issued up-front.
  {
    const int r = tid >> 3, j8 = tid & 7;
    const long grow = (long)blockIdx.x * 64 + r;
    const float* ap = act + grow * 128 + j8 * 16;
    const float* ep = ema + grow * 128 + j8 * 16;

    float pv = (j8 < CLASS_NUM) ? plab[grow * CLASS_NUM + j8] : -3.4e38f;
    f32x4 a4[4], e4[4];
#pragma unroll
    for (int u = 0; u < 4; ++u) a4[u] = *(const f32x4*)(ap + 4 * u);
#pragma unroll
    for (int u = 0; u < 4; ++u) e4[u] = *(const f32x4*)(ep + 4 * u);

    float a2 = 0.f, e2 = 0.f, ae = 0.f;
#pragma unroll
    for (int u = 0; u < 4; ++u) {
      a2 += a4[u].x*a4[u].x + a4[u].y*a4[u].y + a4[u].z*a4[u].z + a4[u].w*a4[u].w;
      e2 += e4[u].x*e4[u].x + e4[u].y*e4[u].y + e4[u].z*e4[u].z + e4[u].w*e4[u].w;
      ae += a4[u].x*e4[u].x + a4[u].y*e4[u].y + a4[u].z*e4[u].z + a4[u].w*e4[u].w;
    }
#pragma unroll
    for (int m = 1; m < 8; m <<= 1) {
      a2 += __shfl_xor(a2, m);
      e2 += __shfl_xor(e2, m);
      ae += __shfl_xor(ae, m);
    }
    const float rna = rsqrtf(a2), rne = rsqrtf(e2);

    // argmax over 7 classes via 8-lane vote (first-max tie rule)
    int bi = j8;
#pragma unroll
    for (int m = 1; m < 8; m <<= 1) {
      const float ov = __shfl_xor(pv, m);
      const int   oi = __shfl_xor(bi, m);
      if (ov > pv || (ov == pv && oi < bi)) { pv = ov; bi = oi; }
    }

    // positive-sum via precomputed class sums (fp32-exact)
    const float* qs = (const float*)(ws + QSUM_OFF) + bi * 128 + j8 * 16;
    float pdot = 0.f;
#pragma unroll
    for (int u = 0; u < 4; ++u) {
      const float4 qv = *(const float4*)(qs + 4 * u);
      pdot += a4[u].x*qv.x + a4[u].y*qv.y + a4[u].z*qv.z + a4[u].w*qv.w;
    }
#pragma unroll
    for (int m = 1; m < 8; m <<= 1) pdot += __shfl_xor(pdot, m);

    if (j8 == 0) {
      s_lpos[r] = ae * rna * rne * C2L;
      s_pd[r]   = pdot * rna;
    }

    // stage A frag-major: addr = s*2048 + (hi_*16 + lr)*32 + k*8   (s = r>>4)
    const float sc = rna * C2L;     // pre-scale so MFMA output is 2s/ln2
    const int s = r >> 4, lr = r & 15, k = j8 >> 1;
#pragma unroll
    for (int h2 = 0; h2 < 2; ++h2) {
      const int hi_ = (j8 & 1) * 2 + h2;
      const f32x4 x = a4[h2 * 2], y = a4[h2 * 2 + 1];
      uint2 u;
      u.x = pk8(x.x * sc, x.y * sc, x.z * sc, x.w * sc);
      u.y = pk8(y.x * sc, y.y * sc, y.z * sc, y.w * sc);
      *(uint2*)(aT + s * 2048 + (hi_ * 16 + lr) * 32 + k * 8) = u;
    }
  }
  __syncthreads();

  // wave role: queue quarter qq, row half rh
  const int qq = wave & 3, rh = wave >> 2;
  const char* As = aT + rh * 4096;
  const long2v la0 = *(const long2v*)(As + lane * 32);
  const long2v la1 = *(const long2v*)(As + lane * 32 + 16);
  const long2v lb0 = *(const long2v*)(As + 2048 + lane * 32);
  const long2v lb1 = *(const long2v*)(As + 2048 + lane * 32 + 16);

  float dn0[4] = {0.f, 0.f, 0.f, 0.f};
  float dn1[4] = {0.f, 0.f, 0.f, 0.f};
  const f32x4 Z = {0.f, 0.f, 0.f, 0.f};
  const char* qp = ws + (size_t)(qq * GPW) * 2048 + (size_t)lane * 32;

  long2v B0a, B0b, B1a, B1b, B2a, B2b;
#define LOADG(Xa, Xb, G)                                                \
  { Xa = *(const long2v*)(qp + (G) * 2048);                             \
    Xb = *(const long2v*)(qp + (G) * 2048 + 16); }
#define COMPG(Xa, Xb)                                                   \
  { f32x4 c0 = Z, c1 = Z;                                               \
    c0 = __builtin_amdgcn_mfma_f32_16x16x32_fp8_fp8(la0[0], Xa[0], c0, 0, 0, 0); \
    c1 = __builtin_amdgcn_mfma_f32_16x16x32_fp8_fp8(lb0[0], Xa[0], c1, 0, 0, 0); \
    c0 = __builtin_amdgcn_mfma_f32_16x16x32_fp8_fp8(la0[1], Xa[1], c0, 0, 0, 0); \
    c1 = __builtin_amdgcn_mfma_f32_16x16x32_fp8_fp8(lb0[1], Xa[1], c1, 0, 0, 0); \
    c0 = __builtin_amdgcn_mfma_f32_16x16x32_fp8_fp8(la1[0], Xb[0], c0, 0, 0, 0); \
    c1 = __builtin_amdgcn_mfma_f32_16x16x32_fp8_fp8(lb1[0], Xb[0], c1, 0, 0, 0); \
    c0 = __builtin_amdgcn_mfma_f32_16x16x32_fp8_fp8(la1[1], Xb[1], c0, 0, 0, 0); \
    c1 = __builtin_amdgcn_mfma_f32_16x16x32_fp8_fp8(lb1[1], Xb[1], c1, 0, 0, 0); \
    _Pragma("unroll")                                                   \
    for (int rg = 0; rg < 4; ++rg) {                                    \
      dn0[rg] += exp2f(c0[rg]);                                         \
      dn1[rg] += exp2f(c1[rg]);                                         \
    } }

  LOADG(B0a, B0b, 0)
  LOADG(B1a, B1b, 1)
  LOADG(B2a, B2b, 2)
#pragma unroll 1
  for (int g = 0; g < GPW - 3; g += 3) {
    COMPG(B0a, B0b) LOADG(B0a, B0b, g + 3)
    COMPG(B1a, B1b) LOADG(B1a, B1b, g + 4)
    COMPG(B2a, B2b) LOADG(B2a, B2b, g + 5)
  }
  COMPG(B0a, B0b)
  COMPG(B1a, B1b)
  COMPG(B2a, B2b)
#undef LOADG
#undef COMPG

  // reduce across the 16 q-column lanes of each row
#pragma unroll
  for (int rg = 0; rg < 4; ++rg)
#pragma unroll
    for (int m = 1; m < 16; m <<= 1) {
      dn0[rg] += __shfl_xor(dn0[rg], m);
      dn1[rg] += __shfl_xor(dn1[rg], m);
    }

  if (lo == 0) {
#pragma unroll
    for (int rg = 0; rg < 4; ++rg) {
      dnp[wave][hi * 4 + rg]      = dn0[rg];   // rows rh*32 + 0..15
      dnp[wave][16 + hi * 4 + rg] = dn1[rg];   // rows rh*32 + 16..31
    }
  }
  __syncthreads();

  // epilogue: thread i (< 64) owns block-row i; partials from the 4 waves
  // of this row-half (w = half*4 + q).
  if (tid < 64) {
    const int i = tid, h4 = (i >> 5) * 4, li = i & 31;
    const float dtot = dnp[h4][li] + dnp[h4 + 1][li] +
                       dnp[h4 + 2][li] + dnp[h4 + 3][li];
    const float lp  = exp2f(s_lpos[i]);        // exp(2*<f,ema_f>)
    const float dnf = lp + dtot - (float)NPAD;
    float loss = -logf(lp / dnf + 1e-8f) + 150.0f * logf(dnf) - 2.0f * s_pd[i];
#pragma unroll
    for (int m = 1; m < 64; m <<= 1) loss += __shfl_xor(loss, m);
    if (tid == 0)
      atomicAdd(out, loss * (1.0f / (151.0f * 65536.0f)));
  }
}

extern "C" void kernel_launch(void* const* d_in, const int* in_sizes, int n_in,
                              void* d_out, int out_size, void* d_ws, size_t ws_size,
                              hipStream_t stream) {
  const float* act   = (const float*)d_in[0];
  const float* ema   = (const float*)d_in[1];
  const float* plab  = (const float*)d_in[2];
  const float* queue = (const float*)d_in[3];
  float* out = (float*)d_out;

  hipMemsetAsync(d_out, 0, sizeof(float), stream);
  hipMemsetAsync((char*)d_ws + QSUM_OFF, 0, CLASS_NUM * 128 * sizeof(float), stream);

  prep_q8<<<dim3(NGRP), dim3(256), 0, stream>>>(queue, (char*)d_ws);

  pgc_stream<<<dim3(65536 / 64), dim3(512), 0, stream>>>(
      act, ema, plab, (const char*)d_ws, out);
}